// Round 9
// baseline (274.531 us; speedup 1.0000x reference)
//
#include <hip/hip_runtime.h>
#include <hip/hip_bf16.h>

#define DIM 256
#define INV_SCALE 0.17677669529663687f   // 1/sqrt(32)
#define SM_EPS 1e-16f
#define BM 128
#define BN 64
#define BK 32

typedef unsigned short ushortT;
typedef unsigned int uintT;
typedef __attribute__((ext_vector_type(8))) __bf16 bf16x8;
typedef __attribute__((ext_vector_type(4))) float f32x4;

// ---------- helpers ----------
__device__ __forceinline__ float bf2f(ushortT u) {
    return __uint_as_float(((uintT)u) << 16);
}
__device__ __forceinline__ ushortT f2bf(float f) {
    uintT u = __float_as_uint(f);
    u += 0x7FFFu + ((u >> 16) & 1u);     // round-to-nearest-even
    return (ushortT)(u >> 16);
}

struct WPack { const void* w[8]; const void* b[8]; };

// inline dtype sniff (proven)
__device__ __forceinline__ bool sniff_m16(const ushortT* __restrict__ x) {
    int lane = threadIdx.x & 63;
    ushortT u = x[lane * 2];
    int e = (u >> 7) & 0xFF;
    bool sane = ((u & 0x7FFFu) == 0) || (e >= 0x66 && e <= 0x90);
    unsigned long long m = __ballot(sane);
    return __popcll(m) >= 32;
}

// ---------- megaA: convx(slot,dom) + convw + zero(counters,state) + flag ----
__global__ __launch_bounds__(256) void megaA(
        const void* __restrict__ xs, const void* __restrict__ xd,
        const ushortT* __restrict__ sniff_src,
        ushortT* __restrict__ xb_s, ushortT* __restrict__ xb_d,
        WPack pk, ushortT* __restrict__ wT, float* __restrict__ biasF,
        int* __restrict__ cnt_s, int* __restrict__ cnt_d,
        uintT* __restrict__ st_s, uintT* __restrict__ st_d,
        int* __restrict__ done, int* __restrict__ flagWs,
        int n4s, int n4d, int Ns_, int Nd_, int nbN_, int nbD_,
        int nA0, int nA1, int nA2)
{
    const bool m16 = sniff_m16(sniff_src);
    const int bid = blockIdx.x;
    const int t = threadIdx.x;

    if (bid < nA0 + nA1) {                       // convert x -> bf16
        const bool d = bid >= nA0;
        const int li = d ? bid - nA0 : bid;
        const int n4 = d ? n4d : n4s;
        const int i = li * 256 + t;
        if (i >= n4) return;
        const void* x = d ? xd : xs;
        ushortT* xb = d ? xb_d : xb_s;
        if (m16) {
            ((ushort4*)xb)[i] = ((const ushort4*)x)[i];
        } else {
            float4 v = ((const float4*)x)[i];
            ushort4 o2;
            o2.x = f2bf(v.x); o2.y = f2bf(v.y); o2.z = f2bf(v.z); o2.w = f2bf(v.w);
            ((ushort4*)xb)[i] = o2;
        }
    } else if (bid < nA0 + nA1 + nA2) {          // weights/biases
        const int r = bid - (nA0 + nA1);
        const int which = r / 257;
        const int j = r % 257;
        if (j == 256) {
            const void* b = pk.b[which];
            float v = m16 ? bf2f(((const ushortT*)b)[t]) : ((const float*)b)[t];
            biasF[which * 256 + t] = v;
        } else {
            const void* w = pk.w[which];
            float v = m16 ? bf2f(((const ushortT*)w)[t * 256 + j])
                          : ((const float*)w)[t * 256 + j];
            wT[(size_t)which * 65536 + j * 256 + t] = f2bf(v);
        }
    } else {                                     // zeroing + flag
        const int li = bid - (nA0 + nA1 + nA2);
        const int idx = li * 256 + t;
        if (idx < Ns_) { cnt_s[idx] = 0; return; }
        int k = idx - Ns_;
        if (k < Nd_) { cnt_d[k] = 0; return; }
        k -= Nd_;
        if (k < nbN_) { st_s[k] = 0; return; }
        k -= nbN_;
        if (k < nbD_) { st_d[k] = 0; return; }
        k -= nbD_;
        if (k == 0) *done = 0;
        else if (k == 1) *flagWs = m16 ? 1 : 0;
    }
}

// ---------- MFMA GEMM core ----------
__device__ __forceinline__ void gemm_core(const ushortT* __restrict__ A,
                                          const ushortT* __restrict__ BT,
                                          int row0, int col0, int M,
                                          f32x4 (&acc)[2][4]) {
    __shared__ ushortT As[BM * BK];
    __shared__ ushortT Bs[BN * BK];
    const int tid  = threadIdx.x;
    const int wid  = tid >> 6;
    const int lane = tid & 63;
    const int r_i = tid >> 2;
    const int kq8 = (tid & 3) << 3;
    const int m   = lane & 15;
    const int q   = lane >> 4;

    const size_t rA0 = (size_t)min(row0 + r_i, M - 1) * DIM;
    const size_t rA1 = (size_t)min(row0 + 64 + r_i, M - 1) * DIM;
    const size_t rB  = (size_t)(col0 + r_i) * DIM;

    for (int k0 = 0; k0 < DIM; k0 += BK) {
        uint4 a0v = *(const uint4*)(A + rA0 + k0 + kq8);
        uint4 a1v = *(const uint4*)(A + rA1 + k0 + kq8);
        uint4 bv  = *(const uint4*)(BT + rB + k0 + kq8);
        __syncthreads();
        *(uint4*)&As[r_i * BK + kq8]        = a0v;
        *(uint4*)&As[(64 + r_i) * BK + kq8] = a1v;
        *(uint4*)&Bs[r_i * BK + kq8]        = bv;
        __syncthreads();

        bf16x8 af0 = *(const bf16x8*)&As[(wid * 32 + m) * BK + q * 8];
        bf16x8 af1 = *(const bf16x8*)&As[(wid * 32 + 16 + m) * BK + q * 8];
        #pragma unroll
        for (int j = 0; j < 4; ++j) {
            bf16x8 bf = *(const bf16x8*)&Bs[(j * 16 + m) * BK + q * 8];
            acc[0][j] = __builtin_amdgcn_mfma_f32_16x16x32_bf16(af0, bf, acc[0][j], 0, 0, 0);
            acc[1][j] = __builtin_amdgcn_mfma_f32_16x16x32_bf16(af1, bf, acc[1][j], 0, 0, 0);
        }
    }
}

// ---------- megaB: QKV GEMM blocks + CSR count blocks in one grid ----------
__global__ __launch_bounds__(256) void megaB(
        const ushortT* __restrict__ xb_s, const ushortT* __restrict__ xb_d,
        const ushortT* __restrict__ wT, const float* __restrict__ biasF,
        ushortT* __restrict__ qkv_s, ushortT* __restrict__ qkv_d,
        size_t zss, size_t zsd, int Ms, int Md, int nbs_, int nbq_,
        const int* __restrict__ dst_s, const int* __restrict__ dst_d,
        int* __restrict__ cnt_s, int* __restrict__ cnt_d, int Es_, int Ed_)
{
    const int bid = blockIdx.x;
    const int nq = nbq_ * 12;
    if (bid >= nq) {                             // edge counting
        const int idx = (bid - nq) * 256 + threadIdx.x;
        if (idx < Es_) atomicAdd(&cnt_s[dst_s[idx]], 1);
        else { int e = idx - Es_; if (e < Ed_) atomicAdd(&cnt_d[dst_d[e]], 1); }
        return;
    }
    const int z  = bid / (nbq_ * 4);
    const int r  = bid % (nbq_ * 4);
    const int by = r / nbq_;
    const int bx0 = r % nbq_;
    const bool dom = bx0 >= nbs_;
    const int bx = dom ? bx0 - nbs_ : bx0;
    const ushortT* A = dom ? xb_d : xb_s;
    const int M = dom ? Md : Ms;
    const int widx = z + (dom ? 4 : 0);
    const ushortT* BT = wT + (size_t)widx * 65536;
    const float* bias = biasF + widx * 256;
    ushortT* C = (dom ? qkv_d : qkv_s) + (size_t)z * (dom ? zsd : zss);

    const int row0 = bx * BM;
    const int col0 = by * BN;
    const int wid = threadIdx.x >> 6, lane = threadIdx.x & 63;
    const int m = lane & 15, q = lane >> 4;

    f32x4 acc[2][4];
    #pragma unroll
    for (int i = 0; i < 2; ++i)
        #pragma unroll
        for (int j = 0; j < 4; ++j) acc[i][j] = (f32x4){0.f, 0.f, 0.f, 0.f};

    gemm_core(A, BT, row0, col0, M, acc);

    #pragma unroll
    for (int i = 0; i < 2; ++i)
        #pragma unroll
        for (int j = 0; j < 4; ++j) {
            const int col = col0 + j * 16 + m;
            const float bval = bias[col];
            #pragma unroll
            for (int rr = 0; rr < 4; ++rr) {
                const int row = row0 + wid * 32 + i * 16 + q * 4 + rr;
                if (row < M)
                    C[(size_t)row * DIM + col] = f2bf(acc[i][j][rr] + bval);
            }
        }
}

// ---------- scan: decoupled lookback over both regions (83 blocks) ----------
__device__ __forceinline__ uintT spack(uintT st, uintT v) { return (st << 30) | v; }

__global__ __launch_bounds__(256) void scan_nodes(
        const int* __restrict__ cnt_s, const int* __restrict__ cnt_d,
        uintT* __restrict__ st_s, uintT* __restrict__ st_d,
        int* __restrict__ rp_s, int* __restrict__ rp_d,
        int* __restrict__ cur_s, int* __restrict__ cur_d,
        int Ns_, int Nd_, int nbN_)
{
    __shared__ int sh[256];
    __shared__ int exclS;
    const int b = blockIdx.x;
    const int t = threadIdx.x;
    const bool dom = b >= nbN_;
    const int lb = dom ? b - nbN_ : b;
    const int N = dom ? Nd_ : Ns_;
    const int* cnt = dom ? cnt_d : cnt_s;
    uintT* st = dom ? st_d : st_s;
    int* rp = dom ? rp_d : rp_s;
    int* cur = dom ? cur_d : cur_s;

    const int i = lb * 256 + t;
    const int v = (i < N) ? cnt[i] : 0;
    sh[t] = v;
    __syncthreads();
    for (int off = 1; off < 256; off <<= 1) {
        int u = (t >= off) ? sh[t - off] : 0;
        __syncthreads();
        sh[t] += u;
        __syncthreads();
    }

    if (t == 0) {
        const uintT agg = (uintT)sh[255];
        uintT excl = 0;
        if (lb == 0) {
            __hip_atomic_store(&st[0], spack(2u, agg), __ATOMIC_RELEASE,
                               __HIP_MEMORY_SCOPE_AGENT);
        } else {
            __hip_atomic_store(&st[lb], spack(1u, agg), __ATOMIC_RELEASE,
                               __HIP_MEMORY_SCOPE_AGENT);
            int j = lb - 1;
            while (j >= 0) {
                uintT s = __hip_atomic_load(&st[j], __ATOMIC_ACQUIRE,
                                            __HIP_MEMORY_SCOPE_AGENT);
                uintT tag = s >> 30;
                if (tag == 2u) { excl += s & 0x3FFFFFFFu; break; }
                if (tag == 1u) { excl += s & 0x3FFFFFFFu; --j; }
            }
            __hip_atomic_store(&st[lb], spack(2u, excl + agg), __ATOMIC_RELEASE,
                               __HIP_MEMORY_SCOPE_AGENT);
        }
        exclS = (int)excl;
    }
    __syncthreads();
    const int excl = exclS;
    if (i < N) {
        const int e = excl + ((t == 0) ? 0 : sh[t - 1]);
        rp[i] = e;
        cur[i] = e;
        if (i == N - 1) rp[N] = e + v;
    }
}

// ---------- scatter: full-width grid, one edge per thread ----------
__global__ __launch_bounds__(256) void scatter_edges(
        const int* __restrict__ ss, const int* __restrict__ ds,
        const int* __restrict__ sd, const int* __restrict__ dd,
        int* __restrict__ cur_s, int* __restrict__ cur_d,
        int* __restrict__ col_s, int* __restrict__ col_d,
        int Es_, int Ed_)
{
    const int idx = blockIdx.x * 256 + threadIdx.x;
    if (idx < Es_) {
        int pos = atomicAdd(&cur_s[ds[idx]], 1);
        col_s[pos] = ss[idx];
    } else {
        int e = idx - Es_;
        if (e < Ed_) {
            int pos = atomicAdd(&cur_d[dd[e]], 1);
            col_d[pos] = sd[e];
        }
    }
}

// ---------- fused attention: 32 lanes/node, uint4 loads, x8 pipeline --------
__global__ __launch_bounds__(256) void attn_kernel(
        const ushortT* __restrict__ Qs, const ushortT* __restrict__ Ks,
        const ushortT* __restrict__ Vs, const int* __restrict__ rps,
        const int* __restrict__ css, ushortT* __restrict__ aggs,
        const ushortT* __restrict__ Qd_, const ushortT* __restrict__ Kd_,
        const ushortT* __restrict__ Vd_, const int* __restrict__ rpd,
        const int* __restrict__ csd, ushortT* __restrict__ aggd,
        int Ns_, int Ntot)
{
    const int sub = threadIdx.x & 31;            // 32 lanes per node
    const int g = blockIdx.x * 8 + (threadIdx.x >> 5);
    if (g >= Ntot) return;
    const bool dom = g >= Ns_;
    const int d = dom ? g - Ns_ : g;
    const ushortT* Qb = dom ? Qd_ : Qs;
    const ushortT* Kb = dom ? Kd_ : Ks;
    const ushortT* Vb = dom ? Vd_ : Vs;
    const int* rowptr = dom ? rpd : rps;
    const int* colsrc = dom ? csd : css;
    ushortT* aggb = dom ? aggd : aggs;

    const int c8 = sub * 8;
    const size_t cbase = (size_t)d * DIM + c8;

    uint4 qv = *(const uint4*)(Qb + cbase);
    float qf[8];
    qf[0] = bf2f((ushortT)(qv.x & 0xFFFF)); qf[1] = bf2f((ushortT)(qv.x >> 16));
    qf[2] = bf2f((ushortT)(qv.y & 0xFFFF)); qf[3] = bf2f((ushortT)(qv.y >> 16));
    qf[4] = bf2f((ushortT)(qv.z & 0xFFFF)); qf[5] = bf2f((ushortT)(qv.z >> 16));
    qf[6] = bf2f((ushortT)(qv.w & 0xFFFF)); qf[7] = bf2f((ushortT)(qv.w >> 16));

    float acc[8] = {};
    float den = 0.f;

    auto PROC = [&](uint4 kv, uint4 vv) {
        float kf[8];
        kf[0] = bf2f((ushortT)(kv.x & 0xFFFF)); kf[1] = bf2f((ushortT)(kv.x >> 16));
        kf[2] = bf2f((ushortT)(kv.y & 0xFFFF)); kf[3] = bf2f((ushortT)(kv.y >> 16));
        kf[4] = bf2f((ushortT)(kv.z & 0xFFFF)); kf[5] = bf2f((ushortT)(kv.z >> 16));
        kf[6] = bf2f((ushortT)(kv.w & 0xFFFF)); kf[7] = bf2f((ushortT)(kv.w >> 16));
        float p = qf[0] * kf[0] + qf[1] * kf[1] + qf[2] * kf[2] + qf[3] * kf[3]
                + qf[4] * kf[4] + qf[5] * kf[5] + qf[6] * kf[6] + qf[7] * kf[7];
        p += __shfl_xor(p, 1, 4);
        p += __shfl_xor(p, 2, 4);
        const float w = __expf(fminf(p * INV_SCALE, 60.0f));
        den += w;
        acc[0] += w * bf2f((ushortT)(vv.x & 0xFFFF));
        acc[1] += w * bf2f((ushortT)(vv.x >> 16));
        acc[2] += w * bf2f((ushortT)(vv.y & 0xFFFF));
        acc[3] += w * bf2f((ushortT)(vv.y >> 16));
        acc[4] += w * bf2f((ushortT)(vv.z & 0xFFFF));
        acc[5] += w * bf2f((ushortT)(vv.z >> 16));
        acc[6] += w * bf2f((ushortT)(vv.w & 0xFFFF));
        acc[7] += w * bf2f((ushortT)(vv.w >> 16));
    };

    const int beg = rowptr[d], end = rowptr[d + 1];
    int i = beg;
    for (; i + 8 <= end; i += 8) {
        uint4 kv[8], vv[8];
        #pragma unroll
        for (int j = 0; j < 8; ++j) {
            const size_t b = (size_t)colsrc[i + j] * DIM + c8;
            kv[j] = *(const uint4*)(Kb + b);
            vv[j] = *(const uint4*)(Vb + b);
        }
        #pragma unroll
        for (int j = 0; j < 8; ++j) PROC(kv[j], vv[j]);
    }
    for (; i + 4 <= end; i += 4) {
        uint4 kv[4], vv[4];
        #pragma unroll
        for (int j = 0; j < 4; ++j) {
            const size_t b = (size_t)colsrc[i + j] * DIM + c8;
            kv[j] = *(const uint4*)(Kb + b);
            vv[j] = *(const uint4*)(Vb + b);
        }
        #pragma unroll
        for (int j = 0; j < 4; ++j) PROC(kv[j], vv[j]);
    }
    for (; i < end; ++i) {
        const size_t sb = (size_t)colsrc[i] * DIM + c8;
        PROC(*(const uint4*)(Kb + sb), *(const uint4*)(Vb + sb));
    }

    const float r = 1.0f / (den + SM_EPS);
    uint4 o;
    o.x = (uintT)f2bf(acc[0] * r) | ((uintT)f2bf(acc[1] * r) << 16);
    o.y = (uintT)f2bf(acc[2] * r) | ((uintT)f2bf(acc[3] * r) << 16);
    o.z = (uintT)f2bf(acc[4] * r) | ((uintT)f2bf(acc[5] * r) << 16);
    o.w = (uintT)f2bf(acc[6] * r) | ((uintT)f2bf(acc[7] * r) << 16);
    *(uint4*)(aggb + cbase) = o;
}

// ---------- OUT GEMM: agg @ wo + bias + residual -> d_out ----------
__global__ __launch_bounds__(256) void gemm_out(
        const ushortT* __restrict__ As_, const ushortT* __restrict__ Ad_,
        const ushortT* __restrict__ wT, const float* __restrict__ biasF,
        const void* __restrict__ xs, const void* __restrict__ xd,
        void* __restrict__ dout, int Ms, int Md, int nbs,
        const int* __restrict__ flag)
{
    const bool dom = (int)blockIdx.x >= nbs;
    const int bx = dom ? blockIdx.x - nbs : blockIdx.x;
    const ushortT* A = dom ? Ad_ : As_;
    const int M = dom ? Md : Ms;
    const int widx = 3 + (dom ? 4 : 0);
    const ushortT* BT = wT + (size_t)widx * 65536;
    const float* bias = biasF + widx * 256;
    const void* res = dom ? xd : xs;
    const size_t outOff = dom ? (size_t)Ms * DIM : 0;

    const int row0 = bx * BM;
    const int col0 = blockIdx.y * BN;
    const int wid = threadIdx.x >> 6, lane = threadIdx.x & 63;
    const int m = lane & 15, q = lane >> 4;

    f32x4 acc[2][4];
    #pragma unroll
    for (int i = 0; i < 2; ++i)
        #pragma unroll
        for (int j = 0; j < 4; ++j) acc[i][j] = (f32x4){0.f, 0.f, 0.f, 0.f};

    gemm_core(A, BT, row0, col0, M, acc);

    const bool m16 = (*flag != 0);
    #pragma unroll
    for (int i = 0; i < 2; ++i)
        #pragma unroll
        for (int j = 0; j < 4; ++j) {
            const int col = col0 + j * 16 + m;
            const float bval = bias[col];
            #pragma unroll
            for (int r = 0; r < 4; ++r) {
                const int row = row0 + wid * 32 + i * 16 + q * 4 + r;
                if (row < M) {
                    const size_t ridx = (size_t)row * DIM + col;
                    float v = acc[i][j][r] + bval;
                    v += m16 ? bf2f(((const ushortT*)res)[ridx])
                             : ((const float*)res)[ridx];
                    if (m16) ((ushortT*)dout)[outOff + ridx] = f2bf(v);
                    else     ((float*)dout)[outOff + ridx] = v;
                }
            }
        }
}

// ---------- host ----------
extern "C" void kernel_launch(void* const* d_in, const int* in_sizes, int n_in,
                              void* d_out, int out_size, void* d_ws, size_t ws_size,
                              hipStream_t stream)
{
    const void* slot_x = d_in[0];
    const void* dom_x  = d_in[1];
    const int* slot_edges = (const int*)d_in[2];
    const int* dom_edges  = (const int*)d_in[3];
    const int Ns = in_sizes[0] / DIM;    // 20000
    const int Nd = in_sizes[1] / DIM;    // 1000
    const int Es = in_sizes[2] / 2;      // 320000
    const int Ed = in_sizes[3] / 2;      // 16000

    WPack pk;
    for (int i = 0; i < 8; ++i) { pk.w[i] = d_in[4 + 2 * i]; pk.b[i] = d_in[5 + 2 * i]; }

    // ---- workspace ----
    char* p = (char*)d_ws;
    size_t o = 0;
    auto take = [&](size_t b) { void* r = p + o; o = (o + b + 255) & ~(size_t)255; return r; };
    const size_t ndS = (size_t)Ns * DIM;
    const size_t ndD = (size_t)Nd * DIM;
    ushortT* xb_s  = (ushortT*)take(ndS * 2);
    ushortT* qkv_s = (ushortT*)take(3 * ndS * 2);
    ushortT* agg_s = (ushortT*)take(ndS * 2);
    ushortT* xb_d  = (ushortT*)take(ndD * 2);
    ushortT* qkv_d = (ushortT*)take(3 * ndD * 2);
    ushortT* agg_d = (ushortT*)take(ndD * 2);
    ushortT* wT    = (ushortT*)take(8 * 65536 * 2);
    float*   biasF = (float*)take(8 * 256 * 4);
    int* rp_s  = (int*)take((size_t)(Ns + 1) * 4);
    int* cur_s = (int*)take((size_t)Ns * 4);
    int* cnt_s = (int*)take((size_t)Ns * 4);
    int* col_s = (int*)take((size_t)Es * 4);
    int* rp_d  = (int*)take((size_t)(Nd + 1) * 4);
    int* cur_d = (int*)take((size_t)Nd * 4);
    int* cnt_d = (int*)take((size_t)Nd * 4);
    int* col_d = (int*)take((size_t)Ed * 4);
    uintT* st_s = (uintT*)take(512 * 4);
    uintT* st_d = (uintT*)take(256 * 4);
    int* done   = (int*)take(256);
    int* flagWs = (int*)take(256);

    const int* src_s = slot_edges;
    const int* dst_s = slot_edges + Es;
    const int* src_d = dom_edges;
    const int* dst_d = dom_edges + Ed;

    const int n4s = Ns * DIM / 4, n4d = Nd * DIM / 4;
    const int nbN = (Ns + 255) / 256;            // 79
    const int nbD = (Nd + 255) / 256;            // 4
    const int nbs = (Ns + BM - 1) / BM;          // 157
    const int nbd = (Nd + BM - 1) / BM;          // 8
    const int nbq = nbs + nbd;                   // 165

    // megaA grid
    const int nA0 = (n4s + 255) / 256;
    const int nA1 = (n4d + 255) / 256;
    const int nA2 = 257 * 8;
    const int nZ  = (Ns + Nd + nbN + nbD + 2 + 255) / 256;
    hipLaunchKernelGGL(megaA, dim3(nA0 + nA1 + nA2 + nZ), dim3(256), 0, stream,
                       slot_x, dom_x, (const ushortT*)slot_x, xb_s, xb_d,
                       pk, wT, biasF, cnt_s, cnt_d, st_s, st_d, done, flagWs,
                       n4s, n4d, Ns, Nd, nbN, nbD, nA0, nA1, nA2);

    // megaB grid: QKV gemm + counting
    const int nCnt = (Es + Ed + 255) / 256;
    hipLaunchKernelGGL(megaB, dim3(nbq * 12 + nCnt), dim3(256), 0, stream,
                       xb_s, xb_d, wT, biasF, qkv_s, qkv_d, ndS, ndD,
                       Ns, Nd, nbs, nbq, dst_s, dst_d, cnt_s, cnt_d, Es, Ed);

    // scan (83 blocks), then full-width scatter (1313 blocks)
    hipLaunchKernelGGL(scan_nodes, dim3(nbN + nbD), dim3(256), 0, stream,
                       cnt_s, cnt_d, st_s, st_d, rp_s, rp_d, cur_s, cur_d,
                       Ns, Nd, nbN);
    hipLaunchKernelGGL(scatter_edges, dim3(nCnt), dim3(256), 0, stream,
                       src_s, dst_s, src_d, dst_d, cur_s, cur_d, col_s, col_d,
                       Es, Ed);

    const int Ntot = Ns + Nd;
    hipLaunchKernelGGL(attn_kernel, dim3((Ntot + 7) / 8), dim3(256), 0, stream,
                       qkv_s, qkv_s + ndS, qkv_s + 2 * ndS, rp_s, col_s, agg_s,
                       qkv_d, qkv_d + ndD, qkv_d + 2 * ndD, rp_d, col_d, agg_d,
                       Ns, Ntot);

    hipLaunchKernelGGL(gemm_out, dim3(nbq, DIM / BN), dim3(256), 0, stream,
                       agg_s, agg_d, wT, biasF, slot_x, dom_x, d_out,
                       Ns, Nd, nbs, flagWs);
}

// Round 10
// 264.119 us; speedup vs baseline: 1.0394x; 1.0394x over previous
//
#include <hip/hip_runtime.h>
#include <hip/hip_bf16.h>

#define DIM 256
#define INV_SCALE 0.17677669529663687f   // 1/sqrt(32)
#define SM_EPS 1e-16f
#define BM 128
#define BN 64
#define BK 32

typedef unsigned short ushortT;
typedef unsigned int uintT;
typedef __attribute__((ext_vector_type(8))) __bf16 bf16x8;
typedef __attribute__((ext_vector_type(4))) float f32x4;

// ---------- helpers ----------
__device__ __forceinline__ float bf2f(ushortT u) {
    return __uint_as_float(((uintT)u) << 16);
}
__device__ __forceinline__ ushortT f2bf(float f) {
    uintT u = __float_as_uint(f);
    u += 0x7FFFu + ((u >> 16) & 1u);     // round-to-nearest-even
    return (ushortT)(u >> 16);
}

struct WPack { const void* w[8]; const void* b[8]; };

// inline dtype sniff (proven)
__device__ __forceinline__ bool sniff_m16(const ushortT* __restrict__ x) {
    int lane = threadIdx.x & 63;
    ushortT u = x[lane * 2];
    int e = (u >> 7) & 0xFF;
    bool sane = ((u & 0x7FFFu) == 0) || (e >= 0x66 && e <= 0x90);
    unsigned long long m = __ballot(sane);
    return __popcll(m) >= 32;
}

// ---------- megaA: convx + coalesced weight transpose + bias + zero + flag --
// block classes: [0,nA0+nA1) convx | [.., +128) wtrans | [.., +8) bias | zero
__global__ __launch_bounds__(256) void megaA(
        const void* __restrict__ xs, const void* __restrict__ xd,
        const ushortT* __restrict__ sniff_src,
        ushortT* __restrict__ xb_s, ushortT* __restrict__ xb_d,
        WPack pk, ushortT* __restrict__ wT, float* __restrict__ biasF,
        int* __restrict__ cnt_s, int* __restrict__ cnt_d,
        uintT* __restrict__ st_s, uintT* __restrict__ st_d,
        int* __restrict__ done, int* __restrict__ flagWs,
        int n4s, int n4d, int Ns_, int Nd_, int nbN_, int nbD_,
        int nA0, int nA1)
{
    const bool m16 = sniff_m16(sniff_src);
    const int bid = blockIdx.x;
    const int t = threadIdx.x;

    if (bid < nA0 + nA1) {                       // convert x -> bf16
        const bool d = bid >= nA0;
        const int li = d ? bid - nA0 : bid;
        const int n4 = d ? n4d : n4s;
        const int i = li * 256 + t;
        if (i >= n4) return;
        const void* x = d ? xd : xs;
        ushortT* xb = d ? xb_d : xb_s;
        if (m16) {
            ((ushort4*)xb)[i] = ((const ushort4*)x)[i];
        } else {
            float4 v = ((const float4*)x)[i];
            ushort4 o2;
            o2.x = f2bf(v.x); o2.y = f2bf(v.y); o2.z = f2bf(v.z); o2.w = f2bf(v.w);
            ((ushort4*)xb)[i] = o2;
        }
    } else if (bid < nA0 + nA1 + 128) {          // weight transpose, 64x64 tiles
        __shared__ float sh[64][65];
        const int r0 = bid - (nA0 + nA1);
        const int which = r0 >> 4;               // 0..7
        const int tile = r0 & 15;
        const int tr = tile >> 2, tc = tile & 3; // k-tile, n-tile
        const void* w = pk.w[which];
        const int tx = t & 63, tg = t >> 6;      // col lane, row group
        #pragma unroll
        for (int i = 0; i < 16; ++i) {
            const int r = i * 4 + tg;
            const size_t si = (size_t)(tr * 64 + r) * 256 + tc * 64 + tx;
            sh[r][tx] = m16 ? bf2f(((const ushortT*)w)[si]) : ((const float*)w)[si];
        }
        __syncthreads();
        ushortT* o = wT + (size_t)which * 65536;
        #pragma unroll
        for (int i = 0; i < 16; ++i) {
            const int r = i * 4 + tg;
            o[(size_t)(tc * 64 + r) * 256 + tr * 64 + tx] = f2bf(sh[tx][r]);
        }
    } else if (bid < nA0 + nA1 + 136) {          // biases
        const int which = bid - (nA0 + nA1 + 128);
        const void* b = pk.b[which];
        float v = m16 ? bf2f(((const ushortT*)b)[t]) : ((const float*)b)[t];
        biasF[which * 256 + t] = v;
    } else {                                     // zeroing + flag
        const int li = bid - (nA0 + nA1 + 136);
        const int idx = li * 256 + t;
        if (idx < Ns_) { cnt_s[idx] = 0; return; }
        int k = idx - Ns_;
        if (k < Nd_) { cnt_d[k] = 0; return; }
        k -= Nd_;
        if (k < nbN_) { st_s[k] = 0; return; }
        k -= nbN_;
        if (k < nbD_) { st_d[k] = 0; return; }
        k -= nbD_;
        if (k == 0) *done = 0;
        else if (k == 1) *flagWs = m16 ? 1 : 0;
    }
}

// ---------- megaB: z-fused QKV GEMM blocks + CSR count blocks ----------
// A-tile staged once in LDS, reused for all 3 weight matrices (24 MFMA/barrier)
__global__ __launch_bounds__(256) void megaB(
        const ushortT* __restrict__ xb_s, const ushortT* __restrict__ xb_d,
        const ushortT* __restrict__ wT, const float* __restrict__ biasF,
        ushortT* __restrict__ qkv_s, ushortT* __restrict__ qkv_d,
        size_t zss, size_t zsd, int Ms, int Md, int nbs_, int nbq_,
        const int* __restrict__ dst_s, const int* __restrict__ dst_d,
        int* __restrict__ cnt_s, int* __restrict__ cnt_d, int Es_, int Ed_)
{
    const int bid = blockIdx.x;
    const int nq = nbq_ * 4;
    if (bid >= nq) {                             // edge counting
        const int idx = (bid - nq) * 256 + threadIdx.x;
        if (idx < Es_) atomicAdd(&cnt_s[dst_s[idx]], 1);
        else { int e = idx - Es_; if (e < Ed_) atomicAdd(&cnt_d[dst_d[e]], 1); }
        return;
    }
    const int by  = bid / nbq_;                  // 0..3 (col tile)
    const int bx0 = bid % nbq_;
    const bool dom = bx0 >= nbs_;
    const int bx = dom ? bx0 - nbs_ : bx0;
    const ushortT* A = dom ? xb_d : xb_s;
    const int M = dom ? Md : Ms;
    const int wbase = dom ? 4 : 0;
    const size_t zstride = dom ? zsd : zss;
    ushortT* Cb = dom ? qkv_d : qkv_s;

    __shared__ ushortT As[BM * BK];
    __shared__ ushortT Bs[3][BN * BK];
    const int tid  = threadIdx.x;
    const int wid  = tid >> 6;
    const int lane = tid & 63;
    const int r_i = tid >> 2;
    const int kq8 = (tid & 3) << 3;
    const int m   = lane & 15;
    const int q   = lane >> 4;
    const int row0 = bx * BM;
    const int col0 = by * BN;

    f32x4 acc[3][2][4];
    #pragma unroll
    for (int z = 0; z < 3; ++z)
        #pragma unroll
        for (int i = 0; i < 2; ++i)
            #pragma unroll
            for (int j = 0; j < 4; ++j)
                acc[z][i][j] = (f32x4){0.f, 0.f, 0.f, 0.f};

    const size_t rA0 = (size_t)min(row0 + r_i, M - 1) * DIM;
    const size_t rA1 = (size_t)min(row0 + 64 + r_i, M - 1) * DIM;
    const size_t rB  = (size_t)(col0 + r_i) * DIM;

    for (int k0 = 0; k0 < DIM; k0 += BK) {
        uint4 a0v = *(const uint4*)(A + rA0 + k0 + kq8);
        uint4 a1v = *(const uint4*)(A + rA1 + k0 + kq8);
        uint4 b0v = *(const uint4*)(wT + (size_t)(wbase + 0) * 65536 + rB + k0 + kq8);
        uint4 b1v = *(const uint4*)(wT + (size_t)(wbase + 1) * 65536 + rB + k0 + kq8);
        uint4 b2v = *(const uint4*)(wT + (size_t)(wbase + 2) * 65536 + rB + k0 + kq8);
        __syncthreads();
        *(uint4*)&As[r_i * BK + kq8]        = a0v;
        *(uint4*)&As[(64 + r_i) * BK + kq8] = a1v;
        *(uint4*)&Bs[0][r_i * BK + kq8]     = b0v;
        *(uint4*)&Bs[1][r_i * BK + kq8]     = b1v;
        *(uint4*)&Bs[2][r_i * BK + kq8]     = b2v;
        __syncthreads();

        bf16x8 af0 = *(const bf16x8*)&As[(wid * 32 + m) * BK + q * 8];
        bf16x8 af1 = *(const bf16x8*)&As[(wid * 32 + 16 + m) * BK + q * 8];
        #pragma unroll
        for (int j = 0; j < 4; ++j) {
            #pragma unroll
            for (int z = 0; z < 3; ++z) {
                bf16x8 bf = *(const bf16x8*)&Bs[z][(j * 16 + m) * BK + q * 8];
                acc[z][0][j] = __builtin_amdgcn_mfma_f32_16x16x32_bf16(af0, bf, acc[z][0][j], 0, 0, 0);
                acc[z][1][j] = __builtin_amdgcn_mfma_f32_16x16x32_bf16(af1, bf, acc[z][1][j], 0, 0, 0);
            }
        }
    }

    #pragma unroll
    for (int z = 0; z < 3; ++z) {
        ushortT* C = Cb + (size_t)z * zstride;
        const float* bias = biasF + (wbase + z) * 256;
        #pragma unroll
        for (int i = 0; i < 2; ++i)
            #pragma unroll
            for (int j = 0; j < 4; ++j) {
                const int col = col0 + j * 16 + m;
                const float bval = bias[col];
                #pragma unroll
                for (int rr = 0; rr < 4; ++rr) {
                    const int row = row0 + wid * 32 + i * 16 + q * 4 + rr;
                    if (row < M)
                        C[(size_t)row * DIM + col] = f2bf(acc[z][i][j][rr] + bval);
                }
            }
    }
}

// ---------- scan: decoupled lookback over both regions (83 blocks) ----------
__device__ __forceinline__ uintT spack(uintT st, uintT v) { return (st << 30) | v; }

__global__ __launch_bounds__(256) void scan_nodes(
        const int* __restrict__ cnt_s, const int* __restrict__ cnt_d,
        uintT* __restrict__ st_s, uintT* __restrict__ st_d,
        int* __restrict__ rp_s, int* __restrict__ rp_d,
        int* __restrict__ cur_s, int* __restrict__ cur_d,
        int Ns_, int Nd_, int nbN_)
{
    __shared__ int sh[256];
    __shared__ int exclS;
    const int b = blockIdx.x;
    const int t = threadIdx.x;
    const bool dom = b >= nbN_;
    const int lb = dom ? b - nbN_ : b;
    const int N = dom ? Nd_ : Ns_;
    const int* cnt = dom ? cnt_d : cnt_s;
    uintT* st = dom ? st_d : st_s;
    int* rp = dom ? rp_d : rp_s;
    int* cur = dom ? cur_d : cur_s;

    const int i = lb * 256 + t;
    const int v = (i < N) ? cnt[i] : 0;
    sh[t] = v;
    __syncthreads();
    for (int off = 1; off < 256; off <<= 1) {
        int u = (t >= off) ? sh[t - off] : 0;
        __syncthreads();
        sh[t] += u;
        __syncthreads();
    }

    if (t == 0) {
        const uintT agg = (uintT)sh[255];
        uintT excl = 0;
        if (lb == 0) {
            __hip_atomic_store(&st[0], spack(2u, agg), __ATOMIC_RELEASE,
                               __HIP_MEMORY_SCOPE_AGENT);
        } else {
            __hip_atomic_store(&st[lb], spack(1u, agg), __ATOMIC_RELEASE,
                               __HIP_MEMORY_SCOPE_AGENT);
            int j = lb - 1;
            while (j >= 0) {
                uintT s = __hip_atomic_load(&st[j], __ATOMIC_ACQUIRE,
                                            __HIP_MEMORY_SCOPE_AGENT);
                uintT tag = s >> 30;
                if (tag == 2u) { excl += s & 0x3FFFFFFFu; break; }
                if (tag == 1u) { excl += s & 0x3FFFFFFFu; --j; }
            }
            __hip_atomic_store(&st[lb], spack(2u, excl + agg), __ATOMIC_RELEASE,
                               __HIP_MEMORY_SCOPE_AGENT);
        }
        exclS = (int)excl;
    }
    __syncthreads();
    const int excl = exclS;
    if (i < N) {
        const int e = excl + ((t == 0) ? 0 : sh[t - 1]);
        rp[i] = e;
        cur[i] = e;
        if (i == N - 1) rp[N] = e + v;
    }
}

// ---------- scatter: full-width grid, one edge per thread ----------
__global__ __launch_bounds__(256) void scatter_edges(
        const int* __restrict__ ss, const int* __restrict__ ds,
        const int* __restrict__ sd, const int* __restrict__ dd,
        int* __restrict__ cur_s, int* __restrict__ cur_d,
        int* __restrict__ col_s, int* __restrict__ col_d,
        int Es_, int Ed_)
{
    const int idx = blockIdx.x * 256 + threadIdx.x;
    if (idx < Es_) {
        int pos = atomicAdd(&cur_s[ds[idx]], 1);
        col_s[pos] = ss[idx];
    } else {
        int e = idx - Es_;
        if (e < Ed_) {
            int pos = atomicAdd(&cur_d[dd[e]], 1);
            col_d[pos] = sd[e];
        }
    }
}

// ---------- fused attention: r7-proven shape (1 wave/node, uint2, x4) -------
__global__ __launch_bounds__(256) void attn_kernel(
        const ushortT* __restrict__ Qs, const ushortT* __restrict__ Ks,
        const ushortT* __restrict__ Vs, const int* __restrict__ rps,
        const int* __restrict__ css, ushortT* __restrict__ aggs,
        const ushortT* __restrict__ Qd_, const ushortT* __restrict__ Kd_,
        const ushortT* __restrict__ Vd_, const int* __restrict__ rpd,
        const int* __restrict__ csd, ushortT* __restrict__ aggd,
        int Ns_, int Ntot)
{
    const int g = blockIdx.x * 4 + (threadIdx.x >> 6);
    if (g >= Ntot) return;
    const bool dom = g >= Ns_;
    const int d = dom ? g - Ns_ : g;
    const int t = threadIdx.x & 63;
    const ushortT* Qb = dom ? Qd_ : Qs;
    const ushortT* Kb = dom ? Kd_ : Ks;
    const ushortT* Vb = dom ? Vd_ : Vs;
    const int* rowptr = dom ? rpd : rps;
    const int* colsrc = dom ? csd : css;
    ushortT* aggb = dom ? aggd : aggs;

    const int t4 = t * 4;
    const size_t cbase = (size_t)d * DIM + t4;
    uint2 qv = *(const uint2*)(Qb + cbase);
    const float q0 = bf2f((ushortT)(qv.x & 0xFFFF)), q1 = bf2f((ushortT)(qv.x >> 16));
    const float q2 = bf2f((ushortT)(qv.y & 0xFFFF)), q3 = bf2f((ushortT)(qv.y >> 16));

    float a0 = 0.f, a1 = 0.f, a2 = 0.f, a3 = 0.f, den = 0.f;

    auto PROC = [&](uint2 kvc, uint2 vvc) {
        float k0 = bf2f((ushortT)(kvc.x & 0xFFFF)), k1 = bf2f((ushortT)(kvc.x >> 16));
        float k2 = bf2f((ushortT)(kvc.y & 0xFFFF)), k3 = bf2f((ushortT)(kvc.y >> 16));
        float p = q0 * k0 + q1 * k1 + q2 * k2 + q3 * k3;
        p += __shfl_xor(p, 1, 8);
        p += __shfl_xor(p, 2, 8);
        p += __shfl_xor(p, 4, 8);
        const float w = __expf(fminf(p * INV_SCALE, 60.0f));
        den += w;
        a0 += w * bf2f((ushortT)(vvc.x & 0xFFFF));
        a1 += w * bf2f((ushortT)(vvc.x >> 16));
        a2 += w * bf2f((ushortT)(vvc.y & 0xFFFF));
        a3 += w * bf2f((ushortT)(vvc.y >> 16));
    };

    const int beg = rowptr[d], end = rowptr[d + 1];
    int i = beg;
    for (; i + 4 <= end; i += 4) {
        const int s0 = colsrc[i], s1 = colsrc[i + 1];
        const int s2 = colsrc[i + 2], s3 = colsrc[i + 3];
        const size_t b0 = (size_t)s0 * DIM + t4, b1 = (size_t)s1 * DIM + t4;
        const size_t b2 = (size_t)s2 * DIM + t4, b3 = (size_t)s3 * DIM + t4;
        uint2 k0v = *(const uint2*)(Kb + b0), v0v = *(const uint2*)(Vb + b0);
        uint2 k1v = *(const uint2*)(Kb + b1), v1v = *(const uint2*)(Vb + b1);
        uint2 k2v = *(const uint2*)(Kb + b2), v2v = *(const uint2*)(Vb + b2);
        uint2 k3v = *(const uint2*)(Kb + b3), v3v = *(const uint2*)(Vb + b3);
        PROC(k0v, v0v); PROC(k1v, v1v); PROC(k2v, v2v); PROC(k3v, v3v);
    }
    for (; i < end; ++i) {
        const size_t sb = (size_t)colsrc[i] * DIM + t4;
        uint2 kv = *(const uint2*)(Kb + sb);
        uint2 vv = *(const uint2*)(Vb + sb);
        PROC(kv, vv);
    }

    const float r = 1.0f / (den + SM_EPS);
    ushort4 o;
    o.x = f2bf(a0 * r); o.y = f2bf(a1 * r); o.z = f2bf(a2 * r); o.w = f2bf(a3 * r);
    *(ushort4*)(aggb + cbase) = o;
}

// ---------- OUT GEMM: agg @ wo + bias + residual -> d_out ----------
__global__ __launch_bounds__(256) void gemm_out(
        const ushortT* __restrict__ As_, const ushortT* __restrict__ Ad_,
        const ushortT* __restrict__ wT, const float* __restrict__ biasF,
        const void* __restrict__ xs, const void* __restrict__ xd,
        void* __restrict__ dout, int Ms, int Md, int nbs,
        const int* __restrict__ flag)
{
    const bool dom = (int)blockIdx.x >= nbs;
    const int bx = dom ? blockIdx.x - nbs : blockIdx.x;
    const ushortT* A = dom ? Ad_ : As_;
    const int M = dom ? Md : Ms;
    const int widx = 3 + (dom ? 4 : 0);
    const ushortT* BT = wT + (size_t)widx * 65536;
    const float* bias = biasF + widx * 256;
    const void* res = dom ? xd : xs;
    const size_t outOff = dom ? (size_t)Ms * DIM : 0;

    __shared__ ushortT As2[BM * BK];
    __shared__ ushortT Bs2[BN * BK];
    const int tid  = threadIdx.x;
    const int wid  = tid >> 6;
    const int lane = tid & 63;
    const int r_i = tid >> 2;
    const int kq8 = (tid & 3) << 3;
    const int m   = lane & 15;
    const int q   = lane >> 4;
    const int row0 = bx * BM;
    const int col0 = blockIdx.y * BN;

    f32x4 acc[2][4];
    #pragma unroll
    for (int i = 0; i < 2; ++i)
        #pragma unroll
        for (int j = 0; j < 4; ++j) acc[i][j] = (f32x4){0.f, 0.f, 0.f, 0.f};

    const size_t rA0 = (size_t)min(row0 + r_i, M - 1) * DIM;
    const size_t rA1 = (size_t)min(row0 + 64 + r_i, M - 1) * DIM;
    const size_t rB  = (size_t)(col0 + r_i) * DIM;

    for (int k0 = 0; k0 < DIM; k0 += BK) {
        uint4 a0v = *(const uint4*)(A + rA0 + k0 + kq8);
        uint4 a1v = *(const uint4*)(A + rA1 + k0 + kq8);
        uint4 bv  = *(const uint4*)(BT + rB + k0 + kq8);
        __syncthreads();
        *(uint4*)&As2[r_i * BK + kq8]        = a0v;
        *(uint4*)&As2[(64 + r_i) * BK + kq8] = a1v;
        *(uint4*)&Bs2[r_i * BK + kq8]        = bv;
        __syncthreads();

        bf16x8 af0 = *(const bf16x8*)&As2[(wid * 32 + m) * BK + q * 8];
        bf16x8 af1 = *(const bf16x8*)&As2[(wid * 32 + 16 + m) * BK + q * 8];
        #pragma unroll
        for (int j = 0; j < 4; ++j) {
            bf16x8 bf = *(const bf16x8*)&Bs2[(j * 16 + m) * BK + q * 8];
            acc[0][j] = __builtin_amdgcn_mfma_f32_16x16x32_bf16(af0, bf, acc[0][j], 0, 0, 0);
            acc[1][j] = __builtin_amdgcn_mfma_f32_16x16x32_bf16(af1, bf, acc[1][j], 0, 0, 0);
        }
    }

    const bool m16 = (*flag != 0);
    #pragma unroll
    for (int i = 0; i < 2; ++i)
        #pragma unroll
        for (int j = 0; j < 4; ++j) {
            const int col = col0 + j * 16 + m;
            const float bval = bias[col];
            #pragma unroll
            for (int r = 0; r < 4; ++r) {
                const int row = row0 + wid * 32 + i * 16 + q * 4 + r;
                if (row < M) {
                    const size_t ridx = (size_t)row * DIM + col;
                    float v = acc[i][j][r] + bval;
                    v += m16 ? bf2f(((const ushortT*)res)[ridx])
                             : ((const float*)res)[ridx];
                    if (m16) ((ushortT*)dout)[outOff + ridx] = f2bf(v);
                    else     ((float*)dout)[outOff + ridx] = v;
                }
            }
        }
}

// ---------- host ----------
extern "C" void kernel_launch(void* const* d_in, const int* in_sizes, int n_in,
                              void* d_out, int out_size, void* d_ws, size_t ws_size,
                              hipStream_t stream)
{
    const void* slot_x = d_in[0];
    const void* dom_x  = d_in[1];
    const int* slot_edges = (const int*)d_in[2];
    const int* dom_edges  = (const int*)d_in[3];
    const int Ns = in_sizes[0] / DIM;    // 20000
    const int Nd = in_sizes[1] / DIM;    // 1000
    const int Es = in_sizes[2] / 2;      // 320000
    const int Ed = in_sizes[3] / 2;      // 16000

    WPack pk;
    for (int i = 0; i < 8; ++i) { pk.w[i] = d_in[4 + 2 * i]; pk.b[i] = d_in[5 + 2 * i]; }

    // ---- workspace ----
    char* p = (char*)d_ws;
    size_t o = 0;
    auto take = [&](size_t b) { void* r = p + o; o = (o + b + 255) & ~(size_t)255; return r; };
    const size_t ndS = (size_t)Ns * DIM;
    const size_t ndD = (size_t)Nd * DIM;
    ushortT* xb_s  = (ushortT*)take(ndS * 2);
    ushortT* qkv_s = (ushortT*)take(3 * ndS * 2);
    ushortT* agg_s = (ushortT*)take(ndS * 2);
    ushortT* xb_d  = (ushortT*)take(ndD * 2);
    ushortT* qkv_d = (ushortT*)take(3 * ndD * 2);
    ushortT* agg_d = (ushortT*)take(ndD * 2);
    ushortT* wT    = (ushortT*)take(8 * 65536 * 2);
    float*   biasF = (float*)take(8 * 256 * 4);
    int* rp_s  = (int*)take((size_t)(Ns + 1) * 4);
    int* cur_s = (int*)take((size_t)Ns * 4);
    int* cnt_s = (int*)take((size_t)Ns * 4);
    int* col_s = (int*)take((size_t)Es * 4);
    int* rp_d  = (int*)take((size_t)(Nd + 1) * 4);
    int* cur_d = (int*)take((size_t)Nd * 4);
    int* cnt_d = (int*)take((size_t)Nd * 4);
    int* col_d = (int*)take((size_t)Ed * 4);
    uintT* st_s = (uintT*)take(512 * 4);
    uintT* st_d = (uintT*)take(256 * 4);
    int* done   = (int*)take(256);
    int* flagWs = (int*)take(256);

    const int* src_s = slot_edges;
    const int* dst_s = slot_edges + Es;
    const int* src_d = dom_edges;
    const int* dst_d = dom_edges + Ed;

    const int n4s = Ns * DIM / 4, n4d = Nd * DIM / 4;
    const int nbN = (Ns + 255) / 256;            // 79
    const int nbD = (Nd + 255) / 256;            // 4
    const int nbs = (Ns + BM - 1) / BM;          // 157
    const int nbd = (Nd + BM - 1) / BM;          // 8
    const int nbq = nbs + nbd;                   // 165

    // megaA grid: convx | 128 wtrans | 8 bias | zero
    const int nA0 = (n4s + 255) / 256;
    const int nA1 = (n4d + 255) / 256;
    const int nZ  = (Ns + Nd + nbN + nbD + 2 + 255) / 256;
    hipLaunchKernelGGL(megaA, dim3(nA0 + nA1 + 136 + nZ), dim3(256), 0, stream,
                       slot_x, dom_x, (const ushortT*)slot_x, xb_s, xb_d,
                       pk, wT, biasF, cnt_s, cnt_d, st_s, st_d, done, flagWs,
                       n4s, n4d, Ns, Nd, nbN, nbD, nA0, nA1);

    // megaB grid: z-fused QKV gemm (nbq*4) + counting
    const int nCnt = (Es + Ed + 255) / 256;
    hipLaunchKernelGGL(megaB, dim3(nbq * 4 + nCnt), dim3(256), 0, stream,
                       xb_s, xb_d, wT, biasF, qkv_s, qkv_d, ndS, ndD,
                       Ns, Nd, nbs, nbq, dst_s, dst_d, cnt_s, cnt_d, Es, Ed);

    // scan (83 blocks), then full-width scatter (1313 blocks)
    hipLaunchKernelGGL(scan_nodes, dim3(nbN + nbD), dim3(256), 0, stream,
                       cnt_s, cnt_d, st_s, st_d, rp_s, rp_d, cur_s, cur_d,
                       Ns, Nd, nbN);
    hipLaunchKernelGGL(scatter_edges, dim3(nCnt), dim3(256), 0, stream,
                       src_s, dst_s, src_d, dst_d, cur_s, cur_d, col_s, col_d,
                       Es, Ed);

    const int Ntot = Ns + Nd;
    hipLaunchKernelGGL(attn_kernel, dim3((Ntot + 3) / 4), dim3(256), 0, stream,
                       qkv_s, qkv_s + ndS, qkv_s + 2 * ndS, rp_s, col_s, agg_s,
                       qkv_d, qkv_d + ndD, qkv_d + 2 * ndD, rp_d, col_d, agg_d,
                       Ns, Ntot);

    hipLaunchKernelGGL(gemm_out, dim3(nbq, DIM / BN), dim3(256), 0, stream,
                       agg_s, agg_d, wT, biasF, slot_x, dom_x, d_out,
                       Ns, Nd, nbs, flagWs);
}

// Round 11
// 263.895 us; speedup vs baseline: 1.0403x; 1.0008x over previous
//
#include <hip/hip_runtime.h>
#include <hip/hip_bf16.h>

#define DIM 256
#define INV_SCALE 0.17677669529663687f   // 1/sqrt(32)
#define SM_EPS 1e-16f
#define BM 128
#define BN 64
#define BK 32
#define LDAS 40   // LDS row stride (ushorts): 80 B = 16B-aligned, 2-way banks max

typedef unsigned short ushortT;
typedef unsigned int uintT;
typedef __attribute__((ext_vector_type(8))) __bf16 bf16x8;
typedef __attribute__((ext_vector_type(4))) float f32x4;

// ---------- helpers ----------
__device__ __forceinline__ float bf2f(ushortT u) {
    return __uint_as_float(((uintT)u) << 16);
}
__device__ __forceinline__ ushortT f2bf(float f) {
    uintT u = __float_as_uint(f);
    u += 0x7FFFu + ((u >> 16) & 1u);     // round-to-nearest-even
    return (ushortT)(u >> 16);
}

struct WPack { const void* w[8]; const void* b[8]; };

// inline dtype sniff (proven)
__device__ __forceinline__ bool sniff_m16(const ushortT* __restrict__ x) {
    int lane = threadIdx.x & 63;
    ushortT u = x[lane * 2];
    int e = (u >> 7) & 0xFF;
    bool sane = ((u & 0x7FFFu) == 0) || (e >= 0x66 && e <= 0x90);
    unsigned long long m = __ballot(sane);
    return __popcll(m) >= 32;
}

// ---------- megaA: convx + coalesced weight transpose + bias + zero + flag --
__global__ __launch_bounds__(256) void megaA(
        const void* __restrict__ xs, const void* __restrict__ xd,
        const ushortT* __restrict__ sniff_src,
        ushortT* __restrict__ xb_s, ushortT* __restrict__ xb_d,
        WPack pk, ushortT* __restrict__ wT, float* __restrict__ biasF,
        int* __restrict__ cnt_s, int* __restrict__ cnt_d,
        uintT* __restrict__ st_s, uintT* __restrict__ st_d,
        int* __restrict__ done, int* __restrict__ flagWs,
        int n4s, int n4d, int Ns_, int Nd_, int nbN_, int nbD_,
        int nA0, int nA1)
{
    const bool m16 = sniff_m16(sniff_src);
    const int bid = blockIdx.x;
    const int t = threadIdx.x;

    if (bid < nA0 + nA1) {                       // convert x -> bf16
        const bool d = bid >= nA0;
        const int li = d ? bid - nA0 : bid;
        const int n4 = d ? n4d : n4s;
        const int i = li * 256 + t;
        if (i >= n4) return;
        const void* x = d ? xd : xs;
        ushortT* xb = d ? xb_d : xb_s;
        if (m16) {
            ((ushort4*)xb)[i] = ((const ushort4*)x)[i];
        } else {
            float4 v = ((const float4*)x)[i];
            ushort4 o2;
            o2.x = f2bf(v.x); o2.y = f2bf(v.y); o2.z = f2bf(v.z); o2.w = f2bf(v.w);
            ((ushort4*)xb)[i] = o2;
        }
    } else if (bid < nA0 + nA1 + 128) {          // weight transpose, 64x64 tiles
        __shared__ float sh[64][65];
        const int r0 = bid - (nA0 + nA1);
        const int which = r0 >> 4;               // 0..7
        const int tile = r0 & 15;
        const int tr = tile >> 2, tc = tile & 3; // k-tile, n-tile
        const void* w = pk.w[which];
        const int tx = t & 63, tg = t >> 6;      // col lane, row group
        #pragma unroll
        for (int i = 0; i < 16; ++i) {
            const int r = i * 4 + tg;
            const size_t si = (size_t)(tr * 64 + r) * 256 + tc * 64 + tx;
            sh[r][tx] = m16 ? bf2f(((const ushortT*)w)[si]) : ((const float*)w)[si];
        }
        __syncthreads();
        ushortT* o = wT + (size_t)which * 65536;
        #pragma unroll
        for (int i = 0; i < 16; ++i) {
            const int r = i * 4 + tg;
            o[(size_t)(tc * 64 + r) * 256 + tr * 64 + tx] = f2bf(sh[tx][r]);
        }
    } else if (bid < nA0 + nA1 + 136) {          // biases
        const int which = bid - (nA0 + nA1 + 128);
        const void* b = pk.b[which];
        float v = m16 ? bf2f(((const ushortT*)b)[t]) : ((const float*)b)[t];
        biasF[which * 256 + t] = v;
    } else {                                     // zeroing + flag
        const int li = bid - (nA0 + nA1 + 136);
        const int idx = li * 256 + t;
        if (idx < Ns_) { cnt_s[idx] = 0; return; }
        int k = idx - Ns_;
        if (k < Nd_) { cnt_d[k] = 0; return; }
        k -= Nd_;
        if (k < nbN_) { st_s[k] = 0; return; }
        k -= nbN_;
        if (k < nbD_) { st_d[k] = 0; return; }
        k -= nbD_;
        if (k == 0) *done = 0;
        else if (k == 1) *flagWs = m16 ? 1 : 0;
    }
}

// ---------- megaB: z-fused QKV GEMM blocks + CSR count blocks ----------
__global__ __launch_bounds__(256) void megaB(
        const ushortT* __restrict__ xb_s, const ushortT* __restrict__ xb_d,
        const ushortT* __restrict__ wT, const float* __restrict__ biasF,
        ushortT* __restrict__ qkv_s, ushortT* __restrict__ qkv_d,
        size_t zss, size_t zsd, int Ms, int Md, int nbs_, int nbq_,
        const int* __restrict__ dst_s, const int* __restrict__ dst_d,
        int* __restrict__ cnt_s, int* __restrict__ cnt_d, int Es_, int Ed_)
{
    const int bid = blockIdx.x;
    const int nq = nbq_ * 4;
    if (bid >= nq) {                             // edge counting
        const int idx = (bid - nq) * 256 + threadIdx.x;
        if (idx < Es_) atomicAdd(&cnt_s[dst_s[idx]], 1);
        else { int e = idx - Es_; if (e < Ed_) atomicAdd(&cnt_d[dst_d[e]], 1); }
        return;
    }
    const int by  = bid / nbq_;                  // 0..3 (col tile)
    const int bx0 = bid % nbq_;
    const bool dom = bx0 >= nbs_;
    const int bx = dom ? bx0 - nbs_ : bx0;
    const ushortT* A = dom ? xb_d : xb_s;
    const int M = dom ? Md : Ms;
    const int wbase = dom ? 4 : 0;
    const size_t zstride = dom ? zsd : zss;
    ushortT* Cb = dom ? qkv_d : qkv_s;

    __shared__ ushortT As[BM * LDAS];
    __shared__ ushortT Bs[3][BN * LDAS];
    const int tid  = threadIdx.x;
    const int wid  = tid >> 6;
    const int lane = tid & 63;
    const int r_i = tid >> 2;
    const int kq8 = (tid & 3) << 3;
    const int m   = lane & 15;
    const int q   = lane >> 4;
    const int row0 = bx * BM;
    const int col0 = by * BN;

    f32x4 acc[3][2][4];
    #pragma unroll
    for (int z = 0; z < 3; ++z)
        #pragma unroll
        for (int i = 0; i < 2; ++i)
            #pragma unroll
            for (int j = 0; j < 4; ++j)
                acc[z][i][j] = (f32x4){0.f, 0.f, 0.f, 0.f};

    const size_t rA0 = (size_t)min(row0 + r_i, M - 1) * DIM;
    const size_t rA1 = (size_t)min(row0 + 64 + r_i, M - 1) * DIM;
    const size_t rB  = (size_t)(col0 + r_i) * DIM;

    for (int k0 = 0; k0 < DIM; k0 += BK) {
        uint4 a0v = *(const uint4*)(A + rA0 + k0 + kq8);
        uint4 a1v = *(const uint4*)(A + rA1 + k0 + kq8);
        uint4 b0v = *(const uint4*)(wT + (size_t)(wbase + 0) * 65536 + rB + k0 + kq8);
        uint4 b1v = *(const uint4*)(wT + (size_t)(wbase + 1) * 65536 + rB + k0 + kq8);
        uint4 b2v = *(const uint4*)(wT + (size_t)(wbase + 2) * 65536 + rB + k0 + kq8);
        __syncthreads();
        *(uint4*)&As[r_i * LDAS + kq8]        = a0v;
        *(uint4*)&As[(64 + r_i) * LDAS + kq8] = a1v;
        *(uint4*)&Bs[0][r_i * LDAS + kq8]     = b0v;
        *(uint4*)&Bs[1][r_i * LDAS + kq8]     = b1v;
        *(uint4*)&Bs[2][r_i * LDAS + kq8]     = b2v;
        __syncthreads();

        bf16x8 af0 = *(const bf16x8*)&As[(wid * 32 + m) * LDAS + q * 8];
        bf16x8 af1 = *(const bf16x8*)&As[(wid * 32 + 16 + m) * LDAS + q * 8];
        #pragma unroll
        for (int j = 0; j < 4; ++j) {
            #pragma unroll
            for (int z = 0; z < 3; ++z) {
                bf16x8 bf = *(const bf16x8*)&Bs[z][(j * 16 + m) * LDAS + q * 8];
                acc[z][0][j] = __builtin_amdgcn_mfma_f32_16x16x32_bf16(af0, bf, acc[z][0][j], 0, 0, 0);
                acc[z][1][j] = __builtin_amdgcn_mfma_f32_16x16x32_bf16(af1, bf, acc[z][1][j], 0, 0, 0);
            }
        }
    }

    #pragma unroll
    for (int z = 0; z < 3; ++z) {
        ushortT* C = Cb + (size_t)z * zstride;
        const float* bias = biasF + (wbase + z) * 256;
        #pragma unroll
        for (int i = 0; i < 2; ++i)
            #pragma unroll
            for (int j = 0; j < 4; ++j) {
                const int col = col0 + j * 16 + m;
                const float bval = bias[col];
                #pragma unroll
                for (int rr = 0; rr < 4; ++rr) {
                    const int row = row0 + wid * 32 + i * 16 + q * 4 + rr;
                    if (row < M)
                        C[(size_t)row * DIM + col] = f2bf(acc[z][i][j][rr] + bval);
                }
            }
    }
}

// ---------- scan: decoupled lookback over both regions (83 blocks) ----------
__device__ __forceinline__ uintT spack(uintT st, uintT v) { return (st << 30) | v; }

__global__ __launch_bounds__(256) void scan_nodes(
        const int* __restrict__ cnt_s, const int* __restrict__ cnt_d,
        uintT* __restrict__ st_s, uintT* __restrict__ st_d,
        int* __restrict__ rp_s, int* __restrict__ rp_d,
        int* __restrict__ cur_s, int* __restrict__ cur_d,
        int Ns_, int Nd_, int nbN_)
{
    __shared__ int sh[256];
    __shared__ int exclS;
    const int b = blockIdx.x;
    const int t = threadIdx.x;
    const bool dom = b >= nbN_;
    const int lb = dom ? b - nbN_ : b;
    const int N = dom ? Nd_ : Ns_;
    const int* cnt = dom ? cnt_d : cnt_s;
    uintT* st = dom ? st_d : st_s;
    int* rp = dom ? rp_d : rp_s;
    int* cur = dom ? cur_d : cur_s;

    const int i = lb * 256 + t;
    const int v = (i < N) ? cnt[i] : 0;
    sh[t] = v;
    __syncthreads();
    for (int off = 1; off < 256; off <<= 1) {
        int u = (t >= off) ? sh[t - off] : 0;
        __syncthreads();
        sh[t] += u;
        __syncthreads();
    }

    if (t == 0) {
        const uintT agg = (uintT)sh[255];
        uintT excl = 0;
        if (lb == 0) {
            __hip_atomic_store(&st[0], spack(2u, agg), __ATOMIC_RELEASE,
                               __HIP_MEMORY_SCOPE_AGENT);
        } else {
            __hip_atomic_store(&st[lb], spack(1u, agg), __ATOMIC_RELEASE,
                               __HIP_MEMORY_SCOPE_AGENT);
            int j = lb - 1;
            while (j >= 0) {
                uintT s = __hip_atomic_load(&st[j], __ATOMIC_ACQUIRE,
                                            __HIP_MEMORY_SCOPE_AGENT);
                uintT tag = s >> 30;
                if (tag == 2u) { excl += s & 0x3FFFFFFFu; break; }
                if (tag == 1u) { excl += s & 0x3FFFFFFFu; --j; }
            }
            __hip_atomic_store(&st[lb], spack(2u, excl + agg), __ATOMIC_RELEASE,
                               __HIP_MEMORY_SCOPE_AGENT);
        }
        exclS = (int)excl;
    }
    __syncthreads();
    const int excl = exclS;
    if (i < N) {
        const int e = excl + ((t == 0) ? 0 : sh[t - 1]);
        rp[i] = e;
        cur[i] = e;
        if (i == N - 1) rp[N] = e + v;
    }
}

// ---------- scatter: full-width grid, one edge per thread ----------
__global__ __launch_bounds__(256) void scatter_edges(
        const int* __restrict__ ss, const int* __restrict__ ds,
        const int* __restrict__ sd, const int* __restrict__ dd,
        int* __restrict__ cur_s, int* __restrict__ cur_d,
        int* __restrict__ col_s, int* __restrict__ col_d,
        int Es_, int Ed_)
{
    const int idx = blockIdx.x * 256 + threadIdx.x;
    if (idx < Es_) {
        int pos = atomicAdd(&cur_s[ds[idx]], 1);
        col_s[pos] = ss[idx];
    } else {
        int e = idx - Es_;
        if (e < Ed_) {
            int pos = atomicAdd(&cur_d[dd[e]], 1);
            col_d[pos] = sd[e];
        }
    }
}

// ---------- fused attention: r7-proven shape (1 wave/node, uint2, x4) -------
__global__ __launch_bounds__(256) void attn_kernel(
        const ushortT* __restrict__ Qs, const ushortT* __restrict__ Ks,
        const ushortT* __restrict__ Vs, const int* __restrict__ rps,
        const int* __restrict__ css, ushortT* __restrict__ aggs,
        const ushortT* __restrict__ Qd_, const ushortT* __restrict__ Kd_,
        const ushortT* __restrict__ Vd_, const int* __restrict__ rpd,
        const int* __restrict__ csd, ushortT* __restrict__ aggd,
        int Ns_, int Ntot)
{
    const int g = blockIdx.x * 4 + (threadIdx.x >> 6);
    if (g >= Ntot) return;
    const bool dom = g >= Ns_;
    const int d = dom ? g - Ns_ : g;
    const int t = threadIdx.x & 63;
    const ushortT* Qb = dom ? Qd_ : Qs;
    const ushortT* Kb = dom ? Kd_ : Ks;
    const ushortT* Vb = dom ? Vd_ : Vs;
    const int* rowptr = dom ? rpd : rps;
    const int* colsrc = dom ? csd : css;
    ushortT* aggb = dom ? aggd : aggs;

    const int t4 = t * 4;
    const size_t cbase = (size_t)d * DIM + t4;
    uint2 qv = *(const uint2*)(Qb + cbase);
    const float q0 = bf2f((ushortT)(qv.x & 0xFFFF)), q1 = bf2f((ushortT)(qv.x >> 16));
    const float q2 = bf2f((ushortT)(qv.y & 0xFFFF)), q3 = bf2f((ushortT)(qv.y >> 16));

    float a0 = 0.f, a1 = 0.f, a2 = 0.f, a3 = 0.f, den = 0.f;

    auto PROC = [&](uint2 kvc, uint2 vvc) {
        float k0 = bf2f((ushortT)(kvc.x & 0xFFFF)), k1 = bf2f((ushortT)(kvc.x >> 16));
        float k2 = bf2f((ushortT)(kvc.y & 0xFFFF)), k3 = bf2f((ushortT)(kvc.y >> 16));
        float p = q0 * k0 + q1 * k1 + q2 * k2 + q3 * k3;
        p += __shfl_xor(p, 1, 8);
        p += __shfl_xor(p, 2, 8);
        p += __shfl_xor(p, 4, 8);
        const float w = __expf(fminf(p * INV_SCALE, 60.0f));
        den += w;
        a0 += w * bf2f((ushortT)(vvc.x & 0xFFFF));
        a1 += w * bf2f((ushortT)(vvc.x >> 16));
        a2 += w * bf2f((ushortT)(vvc.y & 0xFFFF));
        a3 += w * bf2f((ushortT)(vvc.y >> 16));
    };

    const int beg = rowptr[d], end = rowptr[d + 1];
    int i = beg;
    for (; i + 4 <= end; i += 4) {
        const int s0 = colsrc[i], s1 = colsrc[i + 1];
        const int s2 = colsrc[i + 2], s3 = colsrc[i + 3];
        const size_t b0 = (size_t)s0 * DIM + t4, b1 = (size_t)s1 * DIM + t4;
        const size_t b2 = (size_t)s2 * DIM + t4, b3 = (size_t)s3 * DIM + t4;
        uint2 k0v = *(const uint2*)(Kb + b0), v0v = *(const uint2*)(Vb + b0);
        uint2 k1v = *(const uint2*)(Kb + b1), v1v = *(const uint2*)(Vb + b1);
        uint2 k2v = *(const uint2*)(Kb + b2), v2v = *(const uint2*)(Vb + b2);
        uint2 k3v = *(const uint2*)(Kb + b3), v3v = *(const uint2*)(Vb + b3);
        PROC(k0v, v0v); PROC(k1v, v1v); PROC(k2v, v2v); PROC(k3v, v3v);
    }
    for (; i < end; ++i) {
        const size_t sb = (size_t)colsrc[i] * DIM + t4;
        uint2 kv = *(const uint2*)(Kb + sb);
        uint2 vv = *(const uint2*)(Vb + sb);
        PROC(kv, vv);
    }

    const float r = 1.0f / (den + SM_EPS);
    ushort4 o;
    o.x = f2bf(a0 * r); o.y = f2bf(a1 * r); o.z = f2bf(a2 * r); o.w = f2bf(a3 * r);
    *(ushort4*)(aggb + cbase) = o;
}

// ---------- OUT GEMM: agg @ wo + bias + residual -> d_out ----------
__global__ __launch_bounds__(256) void gemm_out(
        const ushortT* __restrict__ As_, const ushortT* __restrict__ Ad_,
        const ushortT* __restrict__ wT, const float* __restrict__ biasF,
        const void* __restrict__ xs, const void* __restrict__ xd,
        void* __restrict__ dout, int Ms, int Md, int nbs,
        const int* __restrict__ flag)
{
    const bool dom = (int)blockIdx.x >= nbs;
    const int bx = dom ? blockIdx.x - nbs : blockIdx.x;
    const ushortT* A = dom ? Ad_ : As_;
    const int M = dom ? Md : Ms;
    const int widx = 3 + (dom ? 4 : 0);
    const ushortT* BT = wT + (size_t)widx * 65536;
    const float* bias = biasF + widx * 256;
    const void* res = dom ? xd : xs;
    const size_t outOff = dom ? (size_t)Ms * DIM : 0;

    __shared__ ushortT As2[BM * LDAS];
    __shared__ ushortT Bs2[BN * LDAS];
    const int tid  = threadIdx.x;
    const int wid  = tid >> 6;
    const int lane = tid & 63;
    const int r_i = tid >> 2;
    const int kq8 = (tid & 3) << 3;
    const int m   = lane & 15;
    const int q   = lane >> 4;
    const int row0 = bx * BM;
    const int col0 = blockIdx.y * BN;

    f32x4 acc[2][4];
    #pragma unroll
    for (int i = 0; i < 2; ++i)
        #pragma unroll
        for (int j = 0; j < 4; ++j) acc[i][j] = (f32x4){0.f, 0.f, 0.f, 0.f};

    const size_t rA0 = (size_t)min(row0 + r_i, M - 1) * DIM;
    const size_t rA1 = (size_t)min(row0 + 64 + r_i, M - 1) * DIM;
    const size_t rB  = (size_t)(col0 + r_i) * DIM;

    for (int k0 = 0; k0 < DIM; k0 += BK) {
        uint4 a0v = *(const uint4*)(A + rA0 + k0 + kq8);
        uint4 a1v = *(const uint4*)(A + rA1 + k0 + kq8);
        uint4 bv  = *(const uint4*)(BT + rB + k0 + kq8);
        __syncthreads();
        *(uint4*)&As2[r_i * LDAS + kq8]        = a0v;
        *(uint4*)&As2[(64 + r_i) * LDAS + kq8] = a1v;
        *(uint4*)&Bs2[r_i * LDAS + kq8]        = bv;
        __syncthreads();

        bf16x8 af0 = *(const bf16x8*)&As2[(wid * 32 + m) * LDAS + q * 8];
        bf16x8 af1 = *(const bf16x8*)&As2[(wid * 32 + 16 + m) * LDAS + q * 8];
        #pragma unroll
        for (int j = 0; j < 4; ++j) {
            bf16x8 bf = *(const bf16x8*)&Bs2[(j * 16 + m) * LDAS + q * 8];
            acc[0][j] = __builtin_amdgcn_mfma_f32_16x16x32_bf16(af0, bf, acc[0][j], 0, 0, 0);
            acc[1][j] = __builtin_amdgcn_mfma_f32_16x16x32_bf16(af1, bf, acc[1][j], 0, 0, 0);
        }
    }

    const bool m16 = (*flag != 0);
    #pragma unroll
    for (int i = 0; i < 2; ++i)
        #pragma unroll
        for (int j = 0; j < 4; ++j) {
            const int col = col0 + j * 16 + m;
            const float bval = bias[col];
            #pragma unroll
            for (int r = 0; r < 4; ++r) {
                const int row = row0 + wid * 32 + i * 16 + q * 4 + r;
                if (row < M) {
                    const size_t ridx = (size_t)row * DIM + col;
                    float v = acc[i][j][r] + bval;
                    v += m16 ? bf2f(((const ushortT*)res)[ridx])
                             : ((const float*)res)[ridx];
                    if (m16) ((ushortT*)dout)[outOff + ridx] = f2bf(v);
                    else     ((float*)dout)[outOff + ridx] = v;
                }
            }
        }
}

// ---------- host ----------
extern "C" void kernel_launch(void* const* d_in, const int* in_sizes, int n_in,
                              void* d_out, int out_size, void* d_ws, size_t ws_size,
                              hipStream_t stream)
{
    const void* slot_x = d_in[0];
    const void* dom_x  = d_in[1];
    const int* slot_edges = (const int*)d_in[2];
    const int* dom_edges  = (const int*)d_in[3];
    const int Ns = in_sizes[0] / DIM;    // 20000
    const int Nd = in_sizes[1] / DIM;    // 1000
    const int Es = in_sizes[2] / 2;      // 320000
    const int Ed = in_sizes[3] / 2;      // 16000

    WPack pk;
    for (int i = 0; i < 8; ++i) { pk.w[i] = d_in[4 + 2 * i]; pk.b[i] = d_in[5 + 2 * i]; }

    // ---- workspace ----
    char* p = (char*)d_ws;
    size_t o = 0;
    auto take = [&](size_t b) { void* r = p + o; o = (o + b + 255) & ~(size_t)255; return r; };
    const size_t ndS = (size_t)Ns * DIM;
    const size_t ndD = (size_t)Nd * DIM;
    ushortT* xb_s  = (ushortT*)take(ndS * 2);
    ushortT* qkv_s = (ushortT*)take(3 * ndS * 2);
    ushortT* agg_s = (ushortT*)take(ndS * 2);
    ushortT* xb_d  = (ushortT*)take(ndD * 2);
    ushortT* qkv_d = (ushortT*)take(3 * ndD * 2);
    ushortT* agg_d = (ushortT*)take(ndD * 2);
    ushortT* wT    = (ushortT*)take(8 * 65536 * 2);
    float*   biasF = (float*)take(8 * 256 * 4);
    int* rp_s  = (int*)take((size_t)(Ns + 1) * 4);
    int* cur_s = (int*)take((size_t)Ns * 4);
    int* cnt_s = (int*)take((size_t)Ns * 4);
    int* col_s = (int*)take((size_t)Es * 4);
    int* rp_d  = (int*)take((size_t)(Nd + 1) * 4);
    int* cur_d = (int*)take((size_t)Nd * 4);
    int* cnt_d = (int*)take((size_t)Nd * 4);
    int* col_d = (int*)take((size_t)Ed * 4);
    uintT* st_s = (uintT*)take(512 * 4);
    uintT* st_d = (uintT*)take(256 * 4);
    int* done   = (int*)take(256);
    int* flagWs = (int*)take(256);

    const int* src_s = slot_edges;
    const int* dst_s = slot_edges + Es;
    const int* src_d = dom_edges;
    const int* dst_d = dom_edges + Ed;

    const int n4s = Ns * DIM / 4, n4d = Nd * DIM / 4;
    const int nbN = (Ns + 255) / 256;            // 79
    const int nbD = (Nd + 255) / 256;            // 4
    const int nbs = (Ns + BM - 1) / BM;          // 157
    const int nbd = (Nd + BM - 1) / BM;          // 8
    const int nbq = nbs + nbd;                   // 165

    // megaA grid: convx | 128 wtrans | 8 bias | zero
    const int nA0 = (n4s + 255) / 256;
    const int nA1 = (n4d + 255) / 256;
    const int nZ  = (Ns + Nd + nbN + nbD + 2 + 255) / 256;
    hipLaunchKernelGGL(megaA, dim3(nA0 + nA1 + 136 + nZ), dim3(256), 0, stream,
                       slot_x, dom_x, (const ushortT*)slot_x, xb_s, xb_d,
                       pk, wT, biasF, cnt_s, cnt_d, st_s, st_d, done, flagWs,
                       n4s, n4d, Ns, Nd, nbN, nbD, nA0, nA1);

    // megaB grid: z-fused QKV gemm (nbq*4) + counting
    const int nCnt = (Es + Ed + 255) / 256;
    hipLaunchKernelGGL(megaB, dim3(nbq * 4 + nCnt), dim3(256), 0, stream,
                       xb_s, xb_d, wT, biasF, qkv_s, qkv_d, ndS, ndD,
                       Ns, Nd, nbs, nbq, dst_s, dst_d, cnt_s, cnt_d, Es, Ed);

    // scan (83 blocks), then full-width scatter (1313 blocks)
    hipLaunchKernelGGL(scan_nodes, dim3(nbN + nbD), dim3(256), 0, stream,
                       cnt_s, cnt_d, st_s, st_d, rp_s, rp_d, cur_s, cur_d,
                       Ns, Nd, nbN);
    hipLaunchKernelGGL(scatter_edges, dim3(nCnt), dim3(256), 0, stream,
                       src_s, dst_s, src_d, dst_d, cur_s, cur_d, col_s, col_d,
                       Es, Ed);

    const int Ntot = Ns + Nd;
    hipLaunchKernelGGL(attn_kernel, dim3((Ntot + 3) / 4), dim3(256), 0, stream,
                       qkv_s, qkv_s + ndS, qkv_s + 2 * ndS, rp_s, col_s, agg_s,
                       qkv_d, qkv_d + ndD, qkv_d + 2 * ndD, rp_d, col_d, agg_d,
                       Ns, Ntot);

    hipLaunchKernelGGL(gemm_out, dim3(nbq, DIM / BN), dim3(256), 0, stream,
                       agg_s, agg_d, wT, biasF, slot_x, dom_x, d_out,
                       Ns, Nd, nbs, flagWs);
}